// Round 10
// baseline (325.850 us; speedup 1.0000x reference)
//
#include <hip/hip_runtime.h>

typedef unsigned short ushort_t;
typedef unsigned int uint_t;
typedef _Float16 f16_t;
typedef _Float16 half8_t __attribute__((ext_vector_type(8)));
typedef float floatx4 __attribute__((ext_vector_type(4)));
typedef unsigned int uintx4 __attribute__((ext_vector_type(4)));

#define LOG2E 1.44269504088896f
#define TWO_LOG2E 2.88539008177793f

__device__ __forceinline__ ushort_t f2h_bits(float f) {
    f16_t h = (f16_t)f;
    return __builtin_bit_cast(ushort_t, h);
}
__device__ __forceinline__ float h2f(ushort_t u) {
    return (float)__builtin_bit_cast(f16_t, u);
}
__device__ __forceinline__ float h2f_lo(uint_t u) { return h2f((ushort_t)(u & 0xFFFF)); }
__device__ __forceinline__ float h2f_hi(uint_t u) { return h2f((ushort_t)(u >> 16)); }

// Gate pre-activations PRE-SCALED by log2e (2*log2e for tanh g-gate) at pack
// time; v_rcp for the divide (no fast-math in harness). tanh=1-2/(1+e^{2g}).
__device__ __forceinline__ float sigm2(float x) {   // x prescaled by log2e
    return __builtin_amdgcn_rcpf(1.0f + __builtin_amdgcn_exp2f(-x));
}
__device__ __forceinline__ float tanh2(float y) {   // y prescaled by 2*log2e
    return __builtin_fmaf(-2.0f, __builtin_amdgcn_rcpf(1.0f + __builtin_amdgcn_exp2f(y)), 1.0f);
}
__device__ __forceinline__ float tanhc(float c) {   // c unscaled (cell state)
    return tanh2(c * TWO_LOG2E);
}

// B-fragment layout everywhere: frag(kt,q,n) at halves ((kt*4+q)*V + n)*8 + j,
// holding B[k][n] with k = kt*32 + q*8 + j. Consecutive n -> contiguous b128.
__device__ __forceinline__ half8_t ldfrag(const ushort_t* p, int V, int kt, int q, int n) {
    return *(const half8_t*)(p + ((size_t)((kt * 4 + q) * V + n)) * 8);
}

// V=512 packs: rows are the 4-gate dim (i,f,g,o at 128 each); g-gate rows get
// 2*log2e, others log2e.
__device__ __forceinline__ void pack_one(
    const float* srcA, int KA, const float* srcB, int KB,
    ushort_t* dst, int V, int K, int idx)
{
    int v = idx / K, k = idx - v * K;
    float val = 0.0f;
    if (k < KA) val = srcA[v * KA + k];
    else if (k < KA + KB) val = srcB[v * KB + (k - KA)];
    float sc = ((v >> 7) == 2) ? TWO_LOG2E : LOG2E;
    int kt = k >> 5, qq = (k >> 3) & 3, j = k & 7;
    dst[((size_t)((kt * 4 + qq) * V + v)) * 8 + j] = f2h_bits(val * sc);
}

// t-LSTM variant: V=768, dead f-gate rows skipped (src row = v<256 ? v : v+256)
// -> packed gate order is i,g,o: v in [256,512) is the tanh g-gate.
__device__ __forceinline__ void pack_tl_one(
    const float* src, int Ksrc, ushort_t* dst, int K, int idx)
{
    int v = idx / K, k = idx - v * K;
    int r = (v < 256) ? v : v + 256;
    float val = (k < Ksrc) ? src[r * Ksrc + k] : 0.0f;
    float sc = (v >= 256 && v < 512) ? TWO_LOG2E : LOG2E;
    int kt = k >> 5, qq = (k >> 3) & 3, j = k & 7;
    dst[((size_t)((kt * 4 + qq) * 768 + v)) * 8 + j] = f2h_bits(val * sc);
}

// All 5 weight packs fused into one launch.
__global__ __launch_bounds__(256) void packAll(
    const float* __restrict__ tWih0, const float* __restrict__ tWih1,
    const float* __restrict__ nWih0, const float* __restrict__ nWhh0,
    const float* __restrict__ nWih1, const float* __restrict__ nWhh1,
    ushort_t* __restrict__ W0m, ushort_t* __restrict__ W1m,
    ushort_t* __restrict__ N0x, ushort_t* __restrict__ N0m,
    ushort_t* __restrict__ N1m)
{
    int idx = blockIdx.x * 256 + threadIdx.x;
    if (idx < 49152) { pack_tl_one(tWih0, 50, W0m, 64, idx); return; }
    idx -= 49152;
    if (idx < 196608) { pack_tl_one(tWih1, 256, W1m, 256, idx); return; }
    idx -= 196608;
    if (idx < 131072) { pack_one(nWih0, 257, (const float*)0, 0, N0x, 512, 256, idx); return; }
    idx -= 131072;
    if (idx < 65536) { pack_one(nWhh0, 128, (const float*)0, 0, N0m, 512, 128, idx); return; }
    idx -= 65536;
    if (idx < 131072) { pack_one(nWih1, 128, nWhh1, 128, N1m, 512, 256, idx); return; }
}

// fusedA R22: 48-row M-tiles (1024 blocks, mt=3) -- the interior point of the
// measured response surface (32-row/6wv/2x-traffic=158us-bucket, 64-row/4wv/
// 1x-traffic=150): traffic x1.33, 3 blocks/CU -> 6 waves/SIMD, and cleaner
// round-quantization (1024/768=1.33 rounds vs 768/512=1.5). LDS 48KB via
// xAa-on-xH2 overlay (xAa dead after GEMM1; xH2 first written after the
// GEMM1->GEMM2 barrier). launch_bounds(512,6) = R13-proven 85-reg budget;
// GEMM3 uses a single-live B-frag to fit.
__global__ __launch_bounds__(512, 6) void fusedA(
    const float* __restrict__ note, const float* __restrict__ targets,
    const ushort_t* __restrict__ W0m, const float* __restrict__ b0,
    const ushort_t* __restrict__ W1m, const float* __restrict__ b1,
    const ushort_t* __restrict__ N0x, const float* __restrict__ nWih0raw,
    const float* __restrict__ nb0,
    uint_t* __restrict__ G1u)
{
    __shared__ __align__(16) ushort_t xH1[48 * 256];   // 24 KB
    __shared__ __align__(16) ushort_t xH2s[48 * 256];  // 24 KB (xAa overlaid)
    ushort_t* xAa = xH2s;   // overlay: only 48*64 halves used, dead pre-GEMM2
    ushort_t* xH2 = xH2s;
    const int tid = threadIdx.x;
    const int wv = tid >> 6, l = tid & 63, l16 = l & 15, q = l >> 4;
    const int r0A = blockIdx.x * 48;

    // staging: features (pitch_pos | pitch_class | vicinity | chord), K 56->64
    for (int idx = tid; idx < 48 * 64; idx += 512) {
        int r = idx >> 6, c = idx & 63;
        int row = r0A + r;
        int b = row / 48, n = row - b * 48;
        float val = 0.0f;
        if (c == 0) val = (float)n * (1.0f / 48.0f);
        else if (c < 13) val = ((n % 12) == (c - 1)) ? 1.0f : 0.0f;
        else if (c < 38) {
            int p = n + (c - 13) - 12;
            if (p >= 0 && p < 48) val = note[b * 48 + p];
        } else if (c < 50) {
            const float* nb = note + b * 48 + (c - 38) * 4;
            val = nb[0] + nb[1] + nb[2] + nb[3];
        }
        int kb = c >> 3, j = c & 7;
        xAa[r * 64 + (((kb ^ r) & 7) << 3) + j] = f2h_bits(val);
    }
    __syncthreads();

    // ---- GEMM1 (K=64) + gate -> xH1 ----
#pragma unroll
    for (int s = 0; s < 2; ++s) {
        const int u = (wv * 2 + s) * 16 + l16;
        floatx4 acc[3][3] = {};
#pragma unroll
        for (int kt = 0; kt < 2; ++kt) {
            half8_t bI = ldfrag(W0m, 768, kt, q, u);
            half8_t bG = ldfrag(W0m, 768, kt, q, 256 + u);
            half8_t bO = ldfrag(W0m, 768, kt, q, 512 + u);
            int kbp = ((kt * 4 + q) ^ l16) & 7;
#pragma unroll
            for (int mt = 0; mt < 3; ++mt) {
                half8_t a = *(const half8_t*)&xAa[(mt * 16 + l16) * 64 + kbp * 8];
                acc[mt][0] = __builtin_amdgcn_mfma_f32_16x16x32_f16(a, bI, acc[mt][0], 0, 0, 0);
                acc[mt][1] = __builtin_amdgcn_mfma_f32_16x16x32_f16(a, bG, acc[mt][1], 0, 0, 0);
                acc[mt][2] = __builtin_amdgcn_mfma_f32_16x16x32_f16(a, bO, acc[mt][2], 0, 0, 0);
            }
        }
        float bi = b0[u] * LOG2E, bg = b0[512 + u] * TWO_LOG2E, bo = b0[768 + u] * LOG2E;
        int kbW = u >> 3;
#pragma unroll
        for (int mt = 0; mt < 3; ++mt)
#pragma unroll
            for (int r = 0; r < 4; ++r) {
                float c = sigm2(acc[mt][0][r] + bi) * tanh2(acc[mt][1][r] + bg);
                float h = sigm2(acc[mt][2][r] + bo) * tanhc(c);
                int m = mt * 16 + q * 4 + r;
                int kbp = (kbW & 16) | ((kbW ^ (m & 15)) & 15);
                xH1[m * 256 + kbp * 8 + (u & 7)] = f2h_bits(h);
            }
    }
    __syncthreads();   // xAa reads complete -> xH2s reusable for xH2

    // ---- GEMM2 (K=256) + gate -> xH2 ----
#pragma unroll
    for (int s = 0; s < 2; ++s) {
        const int u = (wv * 2 + s) * 16 + l16;
        floatx4 acc[3][3] = {};
#pragma unroll
        for (int kt = 0; kt < 8; ++kt) {
            half8_t bI = ldfrag(W1m, 768, kt, q, u);
            half8_t bG = ldfrag(W1m, 768, kt, q, 256 + u);
            half8_t bO = ldfrag(W1m, 768, kt, q, 512 + u);
            int kb = kt * 4 + q;
            int kbp = (kb & 16) | ((kb ^ l16) & 15);
#pragma unroll
            for (int mt = 0; mt < 3; ++mt) {
                half8_t a = *(const half8_t*)&xH1[(mt * 16 + l16) * 256 + kbp * 8];
                acc[mt][0] = __builtin_amdgcn_mfma_f32_16x16x32_f16(a, bI, acc[mt][0], 0, 0, 0);
                acc[mt][1] = __builtin_amdgcn_mfma_f32_16x16x32_f16(a, bG, acc[mt][1], 0, 0, 0);
                acc[mt][2] = __builtin_amdgcn_mfma_f32_16x16x32_f16(a, bO, acc[mt][2], 0, 0, 0);
            }
        }
        float bi = b1[u] * LOG2E, bg = b1[512 + u] * TWO_LOG2E, bo = b1[768 + u] * LOG2E;
        int kbW = u >> 3;
#pragma unroll
        for (int mt = 0; mt < 3; ++mt)
#pragma unroll
            for (int r = 0; r < 4; ++r) {
                float c = sigm2(acc[mt][0][r] + bi) * tanh2(acc[mt][1][r] + bg);
                float h = sigm2(acc[mt][2][r] + bo) * tanhc(c);
                int m = mt * 16 + q * 4 + r;
                int kbp = (kbW & 16) | ((kbW ^ (m & 15)) & 15);
                xH2[m * 256 + kbp * 8 + (u & 7)] = f2h_bits(h);
            }
    }
    __syncthreads();

    // ---- GEMM3 (K=256) + bias + cond rank-1 -> G1 (coalesced uint2 stores) ----
    {
        const int u2 = wv * 16 + l16;
        floatx4 acc[3][4] = {};
#pragma unroll
        for (int kt = 0; kt < 8; ++kt) {
            int kb = kt * 4 + q;
            int kbp = (kb & 16) | ((kb ^ l16) & 15);
            half8_t a[3];
#pragma unroll
            for (int mt = 0; mt < 3; ++mt)
                a[mt] = *(const half8_t*)&xH2[(mt * 16 + l16) * 256 + kbp * 8];
#pragma unroll
            for (int g = 0; g < 4; ++g) {
                half8_t bf = ldfrag(N0x, 512, kt, q, g * 128 + u2);  // single-live
#pragma unroll
                for (int mt = 0; mt < 3; ++mt)
                    acc[mt][g] = __builtin_amdgcn_mfma_f32_16x16x32_f16(a[mt], bf, acc[mt][g], 0, 0, 0);
            }
        }
        float bias[4], wc[4];
#pragma unroll
        for (int g = 0; g < 4; ++g) {
            float sc = (g == 2) ? TWO_LOG2E : LOG2E;
            bias[g] = nb0[g * 128 + u2] * sc;
            wc[g] = nWih0raw[(size_t)(g * 128 + u2) * 257 + 256] * sc;
        }
#pragma unroll
        for (int mt = 0; mt < 3; ++mt) {
#pragma unroll
            for (int r = 0; r < 4; ++r) {
                int R = r0A + mt * 16 + q * 4 + r;
                int b = R / 48;
                int t = R - b * 48;
                float cond = (t > 0) ? targets[R - 1] : 0.0f;
                float vi = acc[mt][0][r] + bias[0] + cond * wc[0];
                float vf = acc[mt][1][r] + bias[1] + cond * wc[1];
                float vg = acc[mt][2][r] + bias[2] + cond * wc[2];
                float vo = acc[mt][3][r] + bias[3] + cond * wc[3];
                uint_t lo = (uint_t)f2h_bits(vi) | ((uint_t)f2h_bits(vf) << 16);
                uint_t hi = (uint_t)f2h_bits(vg) | ((uint_t)f2h_bits(vo) << 16);
                size_t a = ((size_t)(b >> 4) * 48 + t) * 4096 + (b & 15) * 256 + u2 * 2;
                *(uint2*)(G1u + a) = make_uint2(lo, hi);
            }
        }
    }
}

// phaseB: R17/R21 (measured 109.7us, VGPR 120, no spills). Anti-phase wave
// roles; 8 waves, 512 thr, waves_per_eu(2,2) -- the only register config
// proven not to spill. 16-wave layer-split abandoned (3x verified 64-reg
// clamp + MB-scale spills). Structurally near its floor: 64-block parallelism
// is algorithm-capped (B/16), per-step barrier is dependency-forced.
#define MFMA_L1(ACC, A1) do { \
    _Pragma("unroll") for (int kt = 0; kt < 4; ++kt) { \
        int kb = kt * 4 + q; \
        _Pragma("unroll") for (int g = 0; g < 4; ++g) { \
            half8_t bfr = *(const half8_t*)&w1s[((size_t)(kb * 512 + g * 128 + u)) * 8]; \
            ACC[g] = __builtin_amdgcn_mfma_f32_16x16x32_f16(A1[kt], bfr, ACC[g], 0, 0, 0); \
        } } } while (0)

#define MFMA_L2(ACC, A1, A2) do { \
    _Pragma("unroll") for (int kt = 0; kt < 4; ++kt) \
        _Pragma("unroll") for (int g = 0; g < 4; ++g) \
            ACC[g] = __builtin_amdgcn_mfma_f32_16x16x32_f16( \
                A2[kt], __builtin_bit_cast(half8_t, B2[kt + 4][g]), ACC[g], 0, 0, 0); \
    _Pragma("unroll") for (int kt = 0; kt < 4; ++kt) \
        _Pragma("unroll") for (int g = 0; g < 4; ++g) \
            ACC[g] = __builtin_amdgcn_mfma_f32_16x16x32_f16( \
                A1[kt], __builtin_bit_cast(half8_t, B2[kt][g]), ACC[g], 0, 0, 0); \
    } while (0)

#define DO_E2(ACC) do { \
    _Pragma("unroll") for (int r = 0; r < 4; ++r) { \
        float gi = ACC[0][r] + bI; \
        float gf = ACC[1][r] + bF; \
        float gg = ACC[2][r] + bG; \
        float go = ACC[3][r] + bO; \
        c2[r] = sigm2(gf) * c2[r] + sigm2(gi) * tanh2(gg); \
        float h2v = sigm2(go) * tanhc(c2[r]); \
        int m = q * 4 + r; \
        xA[m * 512 + 256 + c + (((kbW ^ m) & 15) << 3) + jW] = f2h_bits(h2v); \
    } } while (0)

#define DO_E1(ACC, GS) do { \
    if (t < 47) { \
        _Pragma("unroll") for (int r = 0; r < 4; ++r) { \
            float gi = ACC[0][r] + h2f_lo(GS[r].x); \
            float gf = ACC[1][r] + h2f_hi(GS[r].x); \
            float gg = ACC[2][r] + h2f_lo(GS[r].y); \
            float go = ACC[3][r] + h2f_hi(GS[r].y); \
            c1[r] = sigm2(gf) * c1[r] + sigm2(gi) * tanh2(gg); \
            float h1v = sigm2(go) * tanhc(c1[r]); \
            int m = q * 4 + r; \
            xA[m * 512 + pv + (((kbW ^ m) & 15) << 3) + jW] = f2h_bits(h1v); \
        } } } while (0)

#define PREF_G1(DST) do { \
    int tn = (t < 46) ? t + 2 : 47; \
    const uint_t* gp = g1base + (size_t)tn * 4096; \
    _Pragma("unroll") for (int r = 0; r < 4; ++r) \
        DST[r] = *(const uint2*)(gp + (q * 4 + r) * 256 + u * 2); \
    } while (0)

__global__ __launch_bounds__(512) __attribute__((amdgpu_waves_per_eu(2, 2)))
void phaseB(
    const uint_t* __restrict__ G1u, const ushort_t* __restrict__ N0m,
    const ushort_t* __restrict__ N1m, const float* __restrict__ nb1,
    const float* __restrict__ outW, const float* __restrict__ outb,
    float* __restrict__ out)
{
    __shared__ __align__(16) ushort_t w1s[16 * 512 * 8];  // 131072 B (Whh0 frags)
    __shared__ __align__(16) ushort_t xA[16 * 512];       // [m][h1b0|h1b1|h2b0|h2b1]
    __shared__ __align__(16) ushort_t owfs[128];          // outW B-frag table, 256 B
    const int tid = threadIdx.x;
    const int wv = tid >> 6, l = tid & 63, l16 = l & 15, q = l >> 4;
    const int role = (wv ^ (wv >> 2)) & 1;
    const int r0 = blockIdx.x * 16;
    const int u = wv * 16 + l16;                 // unit 0..127

    for (int i = tid; i < 8192; i += 512) ((uint4*)w1s)[i] = ((const uint4*)N0m)[i];
    for (int i = tid; i < 1024; i += 512) ((uint4*)xA)[i] = make_uint4(0, 0, 0, 0);
    if (tid < 16) {
        int base = (tid >> 2) * 32 + (tid & 3) * 8;
#pragma unroll
        for (int j = 0; j < 8; ++j)
            owfs[tid * 8 + j] = f2h_bits(outW[base + j] * LOG2E);
    }

    // persistent L2-layer B-frags (128 regs)
    uintx4 B2[8][4];
#pragma unroll
    for (int kt = 0; kt < 8; ++kt)
#pragma unroll
        for (int g = 0; g < 4; ++g)
            B2[kt][g] = *(const uintx4*)(N1m + ((size_t)((kt * 4 + q) * 512 + g * 128 + u)) * 8);

    const float bI = nb1[u] * LOG2E, bF = nb1[128 + u] * LOG2E;
    const float bG = nb1[256 + u] * TWO_LOG2E, bO = nb1[384 + u] * LOG2E;
    const float obs = outb[0] * LOG2E;
    float c1[4], c2[4] = {0, 0, 0, 0};

    const uint_t* g1base = G1u + (size_t)blockIdx.x * 48 * 4096;
    uint2 g1c[4], g1x[4];
#pragma unroll
    for (int r = 0; r < 4; ++r)
        g1c[r] = *(const uint2*)(g1base + (q * 4 + r) * 256 + u * 2);

    const int kbW = u >> 3;   // 0..15
    const int jW = u & 7;

    __syncthreads();   // xA zero + w1s + owfs staged

    // Prologue E1(0): h1(0) from G1(0) only (h1(-1)=0 -> no Whh0 term; c1(-1)=0)
#pragma unroll
    for (int r = 0; r < 4; ++r) {
        float gi = h2f_lo(g1c[r].x);
        float gg = h2f_lo(g1c[r].y);
        float go = h2f_hi(g1c[r].y);
        c1[r] = sigm2(gi) * tanh2(gg);
        float h1v = sigm2(go) * tanhc(c1[r]);
        int m = q * 4 + r;
        xA[m * 512 + (((kbW ^ m) & 15) << 3) + jW] = f2h_bits(h1v);
    }
    // g1c <- G1(1) for region t=0's E1(1)
#pragma unroll
    for (int r = 0; r < 4; ++r)
        g1c[r] = *(const uint2*)(g1base + 4096 + (q * 4 + r) * 256 + u * 2);
    __syncthreads();   // h1(0) visible

    for (int t = 0; t < 48; ++t) {
        // Residency pin: asm "modifies" B2 each iteration -> reload illegal.
#pragma unroll
        for (int kt = 0; kt < 8; ++kt)
#pragma unroll
            for (int g = 0; g < 4; ++g)
                asm volatile("" : "+v"(B2[kt][g]));

        const int c = (t & 1) * 128;   // h1(t) base; h2(t) at 256+c
        const int pv = c ^ 128;        // h1(t+1) dest; h2(t-1) at 256+pv

        // A-fragments: h1(t) (shared by L2-partB and L1) and h2(t-1)
        half8_t a1[4], a2[4];
#pragma unroll
        for (int kt = 0; kt < 4; ++kt) {
            int kb = kt * 4 + q;
            int kbp = (kb ^ l16) & 15;
            a1[kt] = *(const half8_t*)&xA[l16 * 512 + c + kbp * 8];
            a2[kt] = *(const half8_t*)&xA[l16 * 512 + 256 + pv + kbp * 8];
        }

        if (role == 0) {
            // ===== role E: L2 -> E2 -> L1 -> E1 =====
            floatx4 acc2[4] = {};
            MFMA_L2(acc2, a1, a2);
            if (wv == 0) {   // head(t-1) = outW . h2(t-1), wave 0 only
                floatx4 accH = {0.0f, 0.0f, 0.0f, 0.0f};
#pragma unroll
                for (int kt = 0; kt < 4; ++kt) {
                    half8_t of = *(const half8_t*)&owfs[(kt * 4 + q) * 8];
                    accH = __builtin_amdgcn_mfma_f32_16x16x32_f16(a2[kt], of, accH, 0, 0, 0);
                }
                if (t > 0 && l16 == 0) {
#pragma unroll
                    for (int r = 0; r < 4; ++r)
                        out[(r0 + q * 4 + r) * 48 + (t - 1)] = sigm2(accH[r] + obs);
                }
            }
            DO_E2(acc2);
            PREF_G1(g1x);             // early: covered before barrier drain
            floatx4 acc1[4] = {};
            MFMA_L1(acc1, a1);
            DO_E1(acc1, g1c);
#pragma unroll
            for (int r = 0; r < 4; ++r) g1c[r] = g1x[r];
        } else {
            // ===== role O: L1 -> E1 -> L2 -> E2 =====
            floatx4 acc1[4] = {};
            MFMA_L1(acc1, a1);
            DO_E1(acc1, g1c);
            PREF_G1(g1c);             // g1c consumed above; refill directly
            floatx4 acc2[4] = {};
            MFMA_L2(acc2, a1, a2);
            DO_E2(acc2);
        }
        __syncthreads();   // h1(t+1), h2(t) sealed
    }

    // Epilogue: head(47) from h2(47) (at 256+128 after the t=47 region)
    if (wv == 0) {
        floatx4 accH = {0.0f, 0.0f, 0.0f, 0.0f};
#pragma unroll
        for (int kt = 0; kt < 4; ++kt) {
            int kb = kt * 4 + q;
            int kbp = (kb ^ l16) & 15;
            half8_t a2e = *(const half8_t*)&xA[l16 * 512 + 256 + 128 + kbp * 8];
            half8_t of = *(const half8_t*)&owfs[(kt * 4 + q) * 8];
            accH = __builtin_amdgcn_mfma_f32_16x16x32_f16(a2e, of, accH, 0, 0, 0);
        }
        if (l16 == 0) {
#pragma unroll
            for (int r = 0; r < 4; ++r)
                out[(r0 + q * 4 + r) * 48 + 47] = sigm2(accH[r] + obs);
        }
    }
}

extern "C" void kernel_launch(void* const* d_in, const int* in_sizes, int n_in,
                              void* d_out, int out_size, void* d_ws, size_t ws_size,
                              hipStream_t stream)
{
    const float* note  = (const float*)d_in[0];
    const float* targ  = (const float*)d_in[1];
    const float* tWih0 = (const float*)d_in[2];
    const float* tb0   = (const float*)d_in[4];
    const float* tWih1 = (const float*)d_in[5];
    const float* tb1   = (const float*)d_in[7];
    const float* nWih0 = (const float*)d_in[8];
    const float* nWhh0 = (const float*)d_in[9];
    const float* nb0   = (const float*)d_in[10];
    const float* nWih1 = (const float*)d_in[11];
    const float* nWhh1 = (const float*)d_in[12];
    const float* nb1   = (const float*)d_in[13];
    const float* outW  = (const float*)d_in[14];
    const float* outb  = (const float*)d_in[15];

    char* ws = (char*)d_ws;
    uint_t*   G1u = (uint_t*)(ws);                // 64*48*4096 uints = 50331648 B
    ushort_t* W0m = (ushort_t*)(ws + 50331648);   //  98304 B
    ushort_t* W1m = (ushort_t*)(ws + 50429952);   // 393216 B
    ushort_t* N0x = (ushort_t*)(ws + 50823168);   // 262144 B
    ushort_t* N0m = (ushort_t*)(ws + 51085312);   // 131072 B
    ushort_t* N1m = (ushort_t*)(ws + 51216384);   // 262144 B

    packAll<<<2240, 256, 0, stream>>>(tWih0, tWih1, nWih0, nWhh0, nWih1, nWhh1,
                                      W0m, W1m, N0x, N0m, N1m);
    fusedA<<<1024, 512, 0, stream>>>(note, targ, W0m, tb0, W1m, tb1, N0x, nWih0, nb0, G1u);
    phaseB<<<64, 512, 0, stream>>>(G1u, N0m, N1m, nb1, outW, outb, (float*)d_out);
}

// Round 11
// 262.117 us; speedup vs baseline: 1.2431x; 1.2431x over previous
//
#include <hip/hip_runtime.h>

typedef unsigned short ushort_t;
typedef unsigned int uint_t;
typedef _Float16 f16_t;
typedef _Float16 half8_t __attribute__((ext_vector_type(8)));
typedef float floatx4 __attribute__((ext_vector_type(4)));
typedef unsigned int uintx4 __attribute__((ext_vector_type(4)));

#define LOG2E 1.44269504088896f
#define TWO_LOG2E 2.88539008177793f

__device__ __forceinline__ ushort_t f2h_bits(float f) {
    f16_t h = (f16_t)f;
    return __builtin_bit_cast(ushort_t, h);
}
__device__ __forceinline__ float h2f(ushort_t u) {
    return (float)__builtin_bit_cast(f16_t, u);
}
__device__ __forceinline__ float h2f_lo(uint_t u) { return h2f((ushort_t)(u & 0xFFFF)); }
__device__ __forceinline__ float h2f_hi(uint_t u) { return h2f((ushort_t)(u >> 16)); }

// Gate pre-activations PRE-SCALED by log2e (2*log2e for tanh g-gate) at pack
// time; v_rcp for the divide (no fast-math in harness). tanh=1-2/(1+e^{2g}).
__device__ __forceinline__ float sigm2(float x) {   // x prescaled by log2e
    return __builtin_amdgcn_rcpf(1.0f + __builtin_amdgcn_exp2f(-x));
}
__device__ __forceinline__ float tanh2(float y) {   // y prescaled by 2*log2e
    return __builtin_fmaf(-2.0f, __builtin_amdgcn_rcpf(1.0f + __builtin_amdgcn_exp2f(y)), 1.0f);
}
__device__ __forceinline__ float tanhc(float c) {   // c unscaled (cell state)
    return tanh2(c * TWO_LOG2E);
}

// B-fragment layout everywhere: frag(kt,q,n) at halves ((kt*4+q)*V + n)*8 + j,
// holding B[k][n] with k = kt*32 + q*8 + j. Consecutive n -> contiguous b128.
__device__ __forceinline__ half8_t ldfrag(const ushort_t* p, int V, int kt, int q, int n) {
    return *(const half8_t*)(p + ((size_t)((kt * 4 + q) * V + n)) * 8);
}

// V=512 packs: rows are the 4-gate dim (i,f,g,o at 128 each); g-gate rows get
// 2*log2e, others log2e.
__device__ __forceinline__ void pack_one(
    const float* srcA, int KA, const float* srcB, int KB,
    ushort_t* dst, int V, int K, int idx)
{
    int v = idx / K, k = idx - v * K;
    float val = 0.0f;
    if (k < KA) val = srcA[v * KA + k];
    else if (k < KA + KB) val = srcB[v * KB + (k - KA)];
    float sc = ((v >> 7) == 2) ? TWO_LOG2E : LOG2E;
    int kt = k >> 5, qq = (k >> 3) & 3, j = k & 7;
    dst[((size_t)((kt * 4 + qq) * V + v)) * 8 + j] = f2h_bits(val * sc);
}

// t-LSTM variant: V=768, dead f-gate rows skipped (src row = v<256 ? v : v+256)
// -> packed gate order is i,g,o: v in [256,512) is the tanh g-gate.
__device__ __forceinline__ void pack_tl_one(
    const float* src, int Ksrc, ushort_t* dst, int K, int idx)
{
    int v = idx / K, k = idx - v * K;
    int r = (v < 256) ? v : v + 256;
    float val = (k < Ksrc) ? src[r * Ksrc + k] : 0.0f;
    float sc = (v >= 256 && v < 512) ? TWO_LOG2E : LOG2E;
    int kt = k >> 5, qq = (k >> 3) & 3, j = k & 7;
    dst[((size_t)((kt * 4 + qq) * 768 + v)) * 8 + j] = f2h_bits(val * sc);
}

// All 5 weight packs fused into one launch.
__global__ __launch_bounds__(256) void packAll(
    const float* __restrict__ tWih0, const float* __restrict__ tWih1,
    const float* __restrict__ nWih0, const float* __restrict__ nWhh0,
    const float* __restrict__ nWih1, const float* __restrict__ nWhh1,
    ushort_t* __restrict__ W0m, ushort_t* __restrict__ W1m,
    ushort_t* __restrict__ N0x, ushort_t* __restrict__ N0m,
    ushort_t* __restrict__ N1m)
{
    int idx = blockIdx.x * 256 + threadIdx.x;
    if (idx < 49152) { pack_tl_one(tWih0, 50, W0m, 64, idx); return; }
    idx -= 49152;
    if (idx < 196608) { pack_tl_one(tWih1, 256, W1m, 256, idx); return; }
    idx -= 196608;
    if (idx < 131072) { pack_one(nWih0, 257, (const float*)0, 0, N0x, 512, 256, idx); return; }
    idx -= 131072;
    if (idx < 65536) { pack_one(nWhh0, 128, (const float*)0, 0, N0m, 512, 128, idx); return; }
    idx -= 65536;
    if (idx < 131072) { pack_one(nWih1, 128, nWhh1, 128, N1m, 512, 256, idx); return; }
}

// fusedA R23 = R21's 64-row structure + waves_per_eu(4,4) register pin.
// R22's counters exposed fusedA as SPILL-BOUND: VGPR_Count=40, 107MB fetch +
// 276MB write of scratch traffic (the launch_bounds 2nd arg is only a MINIMUM;
// the allocator chases higher occupancy and spills everything). Only min=max
// amdgpu_waves_per_eu has ever produced the intended budget (phaseB (2,2)->120).
// (4,4) -> 128 regs/wave; GEMM3 pressure ~107 fits. LDS 72KB -> 2 blocks/CU
// = 4 waves/SIMD, consistent with the pin.
__global__ __launch_bounds__(512) __attribute__((amdgpu_waves_per_eu(4, 4)))
void fusedA(
    const float* __restrict__ note, const float* __restrict__ targets,
    const ushort_t* __restrict__ W0m, const float* __restrict__ b0,
    const ushort_t* __restrict__ W1m, const float* __restrict__ b1,
    const ushort_t* __restrict__ N0x, const float* __restrict__ nWih0raw,
    const float* __restrict__ nb0,
    uint_t* __restrict__ G1u)
{
    __shared__ __align__(16) ushort_t xAa[64 * 64];    //  8 KB
    __shared__ __align__(16) ushort_t xH1[64 * 256];   // 32 KB
    __shared__ __align__(16) ushort_t xH2[64 * 256];   // 32 KB
    const int tid = threadIdx.x;
    const int wv = tid >> 6, l = tid & 63, l16 = l & 15, q = l >> 4;
    const int r0A = blockIdx.x * 64;

    // staging: features (pitch_pos | pitch_class | vicinity | chord), K 56->64
    for (int idx = tid; idx < 64 * 64; idx += 512) {
        int r = idx >> 6, c = idx & 63;
        int row = r0A + r;
        int b = row / 48, n = row - b * 48;
        float val = 0.0f;
        if (c == 0) val = (float)n * (1.0f / 48.0f);
        else if (c < 13) val = ((n % 12) == (c - 1)) ? 1.0f : 0.0f;
        else if (c < 38) {
            int p = n + (c - 13) - 12;
            if (p >= 0 && p < 48) val = note[b * 48 + p];
        } else if (c < 50) {
            const float* nb = note + b * 48 + (c - 38) * 4;
            val = nb[0] + nb[1] + nb[2] + nb[3];
        }
        int kb = c >> 3, j = c & 7;
        xAa[r * 64 + (((kb ^ r) & 7) << 3) + j] = f2h_bits(val);
    }
    __syncthreads();

    // ---- GEMM1 (K=64) + gate -> xH1 ----
#pragma unroll
    for (int s = 0; s < 2; ++s) {
        const int u = (wv * 2 + s) * 16 + l16;
        floatx4 acc[4][3] = {};
#pragma unroll
        for (int kt = 0; kt < 2; ++kt) {
            half8_t bI = ldfrag(W0m, 768, kt, q, u);
            half8_t bG = ldfrag(W0m, 768, kt, q, 256 + u);
            half8_t bO = ldfrag(W0m, 768, kt, q, 512 + u);
            int kbp = ((kt * 4 + q) ^ l16) & 7;
#pragma unroll
            for (int mt = 0; mt < 4; ++mt) {
                half8_t a = *(const half8_t*)&xAa[(mt * 16 + l16) * 64 + kbp * 8];
                acc[mt][0] = __builtin_amdgcn_mfma_f32_16x16x32_f16(a, bI, acc[mt][0], 0, 0, 0);
                acc[mt][1] = __builtin_amdgcn_mfma_f32_16x16x32_f16(a, bG, acc[mt][1], 0, 0, 0);
                acc[mt][2] = __builtin_amdgcn_mfma_f32_16x16x32_f16(a, bO, acc[mt][2], 0, 0, 0);
            }
        }
        float bi = b0[u] * LOG2E, bg = b0[512 + u] * TWO_LOG2E, bo = b0[768 + u] * LOG2E;
        int kbW = u >> 3;
#pragma unroll
        for (int mt = 0; mt < 4; ++mt)
#pragma unroll
            for (int r = 0; r < 4; ++r) {
                float c = sigm2(acc[mt][0][r] + bi) * tanh2(acc[mt][1][r] + bg);
                float h = sigm2(acc[mt][2][r] + bo) * tanhc(c);
                int m = mt * 16 + q * 4 + r;
                int kbp = (kbW & 16) | ((kbW ^ (m & 15)) & 15);
                xH1[m * 256 + kbp * 8 + (u & 7)] = f2h_bits(h);
            }
    }
    __syncthreads();

    // ---- GEMM2 (K=256) + gate -> xH2 ----
#pragma unroll
    for (int s = 0; s < 2; ++s) {
        const int u = (wv * 2 + s) * 16 + l16;
        floatx4 acc[4][3] = {};
#pragma unroll
        for (int kt = 0; kt < 8; ++kt) {
            half8_t bI = ldfrag(W1m, 768, kt, q, u);
            half8_t bG = ldfrag(W1m, 768, kt, q, 256 + u);
            half8_t bO = ldfrag(W1m, 768, kt, q, 512 + u);
            int kb = kt * 4 + q;
            int kbp = (kb & 16) | ((kb ^ l16) & 15);
#pragma unroll
            for (int mt = 0; mt < 4; ++mt) {
                half8_t a = *(const half8_t*)&xH1[(mt * 16 + l16) * 256 + kbp * 8];
                acc[mt][0] = __builtin_amdgcn_mfma_f32_16x16x32_f16(a, bI, acc[mt][0], 0, 0, 0);
                acc[mt][1] = __builtin_amdgcn_mfma_f32_16x16x32_f16(a, bG, acc[mt][1], 0, 0, 0);
                acc[mt][2] = __builtin_amdgcn_mfma_f32_16x16x32_f16(a, bO, acc[mt][2], 0, 0, 0);
            }
        }
        float bi = b1[u] * LOG2E, bg = b1[512 + u] * TWO_LOG2E, bo = b1[768 + u] * LOG2E;
        int kbW = u >> 3;
#pragma unroll
        for (int mt = 0; mt < 4; ++mt)
#pragma unroll
            for (int r = 0; r < 4; ++r) {
                float c = sigm2(acc[mt][0][r] + bi) * tanh2(acc[mt][1][r] + bg);
                float h = sigm2(acc[mt][2][r] + bo) * tanhc(c);
                int m = mt * 16 + q * 4 + r;
                int kbp = (kbW & 16) | ((kbW ^ (m & 15)) & 15);
                xH2[m * 256 + kbp * 8 + (u & 7)] = f2h_bits(h);
            }
    }
    __syncthreads();

    // ---- GEMM3 (K=256) + bias + cond rank-1 -> G1 (coalesced uint2 stores) ----
    {
        const int u2 = wv * 16 + l16;
        floatx4 acc[4][4] = {};
#pragma unroll
        for (int kt = 0; kt < 8; ++kt) {
            half8_t bf[4];
#pragma unroll
            for (int g = 0; g < 4; ++g) bf[g] = ldfrag(N0x, 512, kt, q, g * 128 + u2);
            int kb = kt * 4 + q;
            int kbp = (kb & 16) | ((kb ^ l16) & 15);
#pragma unroll
            for (int mt = 0; mt < 4; ++mt) {
                half8_t a = *(const half8_t*)&xH2[(mt * 16 + l16) * 256 + kbp * 8];
#pragma unroll
                for (int g = 0; g < 4; ++g)
                    acc[mt][g] = __builtin_amdgcn_mfma_f32_16x16x32_f16(a, bf[g], acc[mt][g], 0, 0, 0);
            }
        }
        float bias[4], wc[4];
#pragma unroll
        for (int g = 0; g < 4; ++g) {
            float sc = (g == 2) ? TWO_LOG2E : LOG2E;
            bias[g] = nb0[g * 128 + u2] * sc;
            wc[g] = nWih0raw[(size_t)(g * 128 + u2) * 257 + 256] * sc;
        }
#pragma unroll
        for (int mt = 0; mt < 4; ++mt) {
#pragma unroll
            for (int r = 0; r < 4; ++r) {
                int R = r0A + mt * 16 + q * 4 + r;
                int b = R / 48;
                int t = R - b * 48;
                float cond = (t > 0) ? targets[R - 1] : 0.0f;
                float vi = acc[mt][0][r] + bias[0] + cond * wc[0];
                float vf = acc[mt][1][r] + bias[1] + cond * wc[1];
                float vg = acc[mt][2][r] + bias[2] + cond * wc[2];
                float vo = acc[mt][3][r] + bias[3] + cond * wc[3];
                uint_t lo = (uint_t)f2h_bits(vi) | ((uint_t)f2h_bits(vf) << 16);
                uint_t hi = (uint_t)f2h_bits(vg) | ((uint_t)f2h_bits(vo) << 16);
                size_t a = ((size_t)(b >> 4) * 48 + t) * 4096 + (b & 15) * 256 + u2 * 2;
                *(uint2*)(G1u + a) = make_uint2(lo, hi);
            }
        }
    }
}

// phaseB: R17/R21 (measured 109.7us, VGPR 120, no spills). Anti-phase wave
// roles; 8 waves, 512 thr, waves_per_eu(2,2) -- the only register config
// proven not to spill.
#define MFMA_L1(ACC, A1) do { \
    _Pragma("unroll") for (int kt = 0; kt < 4; ++kt) { \
        int kb = kt * 4 + q; \
        _Pragma("unroll") for (int g = 0; g < 4; ++g) { \
            half8_t bfr = *(const half8_t*)&w1s[((size_t)(kb * 512 + g * 128 + u)) * 8]; \
            ACC[g] = __builtin_amdgcn_mfma_f32_16x16x32_f16(A1[kt], bfr, ACC[g], 0, 0, 0); \
        } } } while (0)

#define MFMA_L2(ACC, A1, A2) do { \
    _Pragma("unroll") for (int kt = 0; kt < 4; ++kt) \
        _Pragma("unroll") for (int g = 0; g < 4; ++g) \
            ACC[g] = __builtin_amdgcn_mfma_f32_16x16x32_f16( \
                A2[kt], __builtin_bit_cast(half8_t, B2[kt + 4][g]), ACC[g], 0, 0, 0); \
    _Pragma("unroll") for (int kt = 0; kt < 4; ++kt) \
        _Pragma("unroll") for (int g = 0; g < 4; ++g) \
            ACC[g] = __builtin_amdgcn_mfma_f32_16x16x32_f16( \
                A1[kt], __builtin_bit_cast(half8_t, B2[kt][g]), ACC[g], 0, 0, 0); \
    } while (0)

#define DO_E2(ACC) do { \
    _Pragma("unroll") for (int r = 0; r < 4; ++r) { \
        float gi = ACC[0][r] + bI; \
        float gf = ACC[1][r] + bF; \
        float gg = ACC[2][r] + bG; \
        float go = ACC[3][r] + bO; \
        c2[r] = sigm2(gf) * c2[r] + sigm2(gi) * tanh2(gg); \
        float h2v = sigm2(go) * tanhc(c2[r]); \
        int m = q * 4 + r; \
        xA[m * 512 + 256 + c + (((kbW ^ m) & 15) << 3) + jW] = f2h_bits(h2v); \
    } } while (0)

#define DO_E1(ACC, GS) do { \
    if (t < 47) { \
        _Pragma("unroll") for (int r = 0; r < 4; ++r) { \
            float gi = ACC[0][r] + h2f_lo(GS[r].x); \
            float gf = ACC[1][r] + h2f_hi(GS[r].x); \
            float gg = ACC[2][r] + h2f_lo(GS[r].y); \
            float go = ACC[3][r] + h2f_hi(GS[r].y); \
            c1[r] = sigm2(gf) * c1[r] + sigm2(gi) * tanh2(gg); \
            float h1v = sigm2(go) * tanhc(c1[r]); \
            int m = q * 4 + r; \
            xA[m * 512 + pv + (((kbW ^ m) & 15) << 3) + jW] = f2h_bits(h1v); \
        } } } while (0)

#define PREF_G1(DST) do { \
    int tn = (t < 46) ? t + 2 : 47; \
    const uint_t* gp = g1base + (size_t)tn * 4096; \
    _Pragma("unroll") for (int r = 0; r < 4; ++r) \
        DST[r] = *(const uint2*)(gp + (q * 4 + r) * 256 + u * 2); \
    } while (0)

__global__ __launch_bounds__(512) __attribute__((amdgpu_waves_per_eu(2, 2)))
void phaseB(
    const uint_t* __restrict__ G1u, const ushort_t* __restrict__ N0m,
    const ushort_t* __restrict__ N1m, const float* __restrict__ nb1,
    const float* __restrict__ outW, const float* __restrict__ outb,
    float* __restrict__ out)
{
    __shared__ __align__(16) ushort_t w1s[16 * 512 * 8];  // 131072 B (Whh0 frags)
    __shared__ __align__(16) ushort_t xA[16 * 512];       // [m][h1b0|h1b1|h2b0|h2b1]
    __shared__ __align__(16) ushort_t owfs[128];          // outW B-frag table, 256 B
    const int tid = threadIdx.x;
    const int wv = tid >> 6, l = tid & 63, l16 = l & 15, q = l >> 4;
    const int role = (wv ^ (wv >> 2)) & 1;
    const int r0 = blockIdx.x * 16;
    const int u = wv * 16 + l16;                 // unit 0..127

    for (int i = tid; i < 8192; i += 512) ((uint4*)w1s)[i] = ((const uint4*)N0m)[i];
    for (int i = tid; i < 1024; i += 512) ((uint4*)xA)[i] = make_uint4(0, 0, 0, 0);
    if (tid < 16) {
        int base = (tid >> 2) * 32 + (tid & 3) * 8;
#pragma unroll
        for (int j = 0; j < 8; ++j)
            owfs[tid * 8 + j] = f2h_bits(outW[base + j] * LOG2E);
    }

    // persistent L2-layer B-frags (128 regs)
    uintx4 B2[8][4];
#pragma unroll
    for (int kt = 0; kt < 8; ++kt)
#pragma unroll
        for (int g = 0; g < 4; ++g)
            B2[kt][g] = *(const uintx4*)(N1m + ((size_t)((kt * 4 + q) * 512 + g * 128 + u)) * 8);

    const float bI = nb1[u] * LOG2E, bF = nb1[128 + u] * LOG2E;
    const float bG = nb1[256 + u] * TWO_LOG2E, bO = nb1[384 + u] * LOG2E;
    const float obs = outb[0] * LOG2E;
    float c1[4], c2[4] = {0, 0, 0, 0};

    const uint_t* g1base = G1u + (size_t)blockIdx.x * 48 * 4096;
    uint2 g1c[4], g1x[4];
#pragma unroll
    for (int r = 0; r < 4; ++r)
        g1c[r] = *(const uint2*)(g1base + (q * 4 + r) * 256 + u * 2);

    const int kbW = u >> 3;   // 0..15
    const int jW = u & 7;

    __syncthreads();   // xA zero + w1s + owfs staged

    // Prologue E1(0): h1(0) from G1(0) only (h1(-1)=0 -> no Whh0 term; c1(-1)=0)
#pragma unroll
    for (int r = 0; r < 4; ++r) {
        float gi = h2f_lo(g1c[r].x);
        float gg = h2f_lo(g1c[r].y);
        float go = h2f_hi(g1c[r].y);
        c1[r] = sigm2(gi) * tanh2(gg);
        float h1v = sigm2(go) * tanhc(c1[r]);
        int m = q * 4 + r;
        xA[m * 512 + (((kbW ^ m) & 15) << 3) + jW] = f2h_bits(h1v);
    }
    // g1c <- G1(1) for region t=0's E1(1)
#pragma unroll
    for (int r = 0; r < 4; ++r)
        g1c[r] = *(const uint2*)(g1base + 4096 + (q * 4 + r) * 256 + u * 2);
    __syncthreads();   // h1(0) visible

    for (int t = 0; t < 48; ++t) {
        // Residency pin: asm "modifies" B2 each iteration -> reload illegal.
#pragma unroll
        for (int kt = 0; kt < 8; ++kt)
#pragma unroll
            for (int g = 0; g < 4; ++g)
                asm volatile("" : "+v"(B2[kt][g]));

        const int c = (t & 1) * 128;   // h1(t) base; h2(t) at 256+c
        const int pv = c ^ 128;        // h1(t+1) dest; h2(t-1) at 256+pv

        // A-fragments: h1(t) (shared by L2-partB and L1) and h2(t-1)
        half8_t a1[4], a2[4];
#pragma unroll
        for (int kt = 0; kt < 4; ++kt) {
            int kb = kt * 4 + q;
            int kbp = (kb ^ l16) & 15;
            a1[kt] = *(const half8_t*)&xA[l16 * 512 + c + kbp * 8];
            a2[kt] = *(const half8_t*)&xA[l16 * 512 + 256 + pv + kbp * 8];
        }

        if (role == 0) {
            // ===== role E: L2 -> E2 -> L1 -> E1 =====
            floatx4 acc2[4] = {};
            MFMA_L2(acc2, a1, a2);
            if (wv == 0) {   // head(t-1) = outW . h2(t-1), wave 0 only
                floatx4 accH = {0.0f, 0.0f, 0.0f, 0.0f};
#pragma unroll
                for (int kt = 0; kt < 4; ++kt) {
                    half8_t of = *(const half8_t*)&owfs[(kt * 4 + q) * 8];
                    accH = __builtin_amdgcn_mfma_f32_16x16x32_f16(a2[kt], of, accH, 0, 0, 0);
                }
                if (t > 0 && l16 == 0) {
#pragma unroll
                    for (int r = 0; r < 4; ++r)
                        out[(r0 + q * 4 + r) * 48 + (t - 1)] = sigm2(accH[r] + obs);
                }
            }
            DO_E2(acc2);
            PREF_G1(g1x);             // early: covered before barrier drain
            floatx4 acc1[4] = {};
            MFMA_L1(acc1, a1);
            DO_E1(acc1, g1c);
#pragma unroll
            for (int r = 0; r < 4; ++r) g1c[r] = g1x[r];
        } else {
            // ===== role O: L1 -> E1 -> L2 -> E2 =====
            floatx4 acc1[4] = {};
            MFMA_L1(acc1, a1);
            DO_E1(acc1, g1c);
            PREF_G1(g1c);             // g1c consumed above; refill directly
            floatx4 acc2[4] = {};
            MFMA_L2(acc2, a1, a2);
            DO_E2(acc2);
        }
        __syncthreads();   // h1(t+1), h2(t) sealed
    }

    // Epilogue: head(47) from h2(47) (at 256+128 after the t=47 region)
    if (wv == 0) {
        floatx4 accH = {0.0f, 0.0f, 0.0f, 0.0f};
#pragma unroll
        for (int kt = 0; kt < 4; ++kt) {
            int kb = kt * 4 + q;
            int kbp = (kb ^ l16) & 15;
            half8_t a2e = *(const half8_t*)&xA[l16 * 512 + 256 + 128 + kbp * 8];
            half8_t of = *(const half8_t*)&owfs[(kt * 4 + q) * 8];
            accH = __builtin_amdgcn_mfma_f32_16x16x32_f16(a2e, of, accH, 0, 0, 0);
        }
        if (l16 == 0) {
#pragma unroll
            for (int r = 0; r < 4; ++r)
                out[(r0 + q * 4 + r) * 48 + 47] = sigm2(accH[r] + obs);
        }
    }
}

extern "C" void kernel_launch(void* const* d_in, const int* in_sizes, int n_in,
                              void* d_out, int out_size, void* d_ws, size_t ws_size,
                              hipStream_t stream)
{
    const float* note  = (const float*)d_in[0];
    const float* targ  = (const float*)d_in[1];
    const float* tWih0 = (const float*)d_in[2];
    const float* tb0   = (const float*)d_in[4];
    const float* tWih1 = (const float*)d_in[5];
    const float* tb1   = (const float*)d_in[7];
    const float* nWih0 = (const float*)d_in[8];
    const float* nWhh0 = (const float*)d_in[9];
    const float* nb0   = (const float*)d_in[10];
    const float* nWih1 = (const float*)d_in[11];
    const float* nWhh1 = (const float*)d_in[12];
    const float* nb1   = (const float*)d_in[13];
    const float* outW  = (const float*)d_in[14];
    const float* outb  = (const float*)d_in[15];

    char* ws = (char*)d_ws;
    uint_t*   G1u = (uint_t*)(ws);                // 64*48*4096 uints = 50331648 B
    ushort_t* W0m = (ushort_t*)(ws + 50331648);   //  98304 B
    ushort_t* W1m = (ushort_t*)(ws + 50429952);   // 393216 B
    ushort_t* N0x = (ushort_t*)(ws + 50823168);   // 262144 B
    ushort_t* N0m = (ushort_t*)(ws + 51085312);   // 131072 B
    ushort_t* N1m = (ushort_t*)(ws + 51216384);   // 262144 B

    packAll<<<2240, 256, 0, stream>>>(tWih0, tWih1, nWih0, nWhh0, nWih1, nWhh1,
                                      W0m, W1m, N0x, N0m, N1m);
    fusedA<<<768, 512, 0, stream>>>(note, targ, W0m, tb0, W1m, tb1, N0x, nWih0, nb0, G1u);
    phaseB<<<64, 512, 0, stream>>>(G1u, N0m, N1m, nb1, outW, outb, (float*)d_out);
}

// Round 12
// 258.725 us; speedup vs baseline: 1.2594x; 1.0131x over previous
//
#include <hip/hip_runtime.h>

typedef unsigned short ushort_t;
typedef unsigned int uint_t;
typedef _Float16 f16_t;
typedef _Float16 half8_t __attribute__((ext_vector_type(8)));
typedef float floatx4 __attribute__((ext_vector_type(4)));
typedef unsigned int uintx4 __attribute__((ext_vector_type(4)));

#define LOG2E 1.44269504088896f
#define TWO_LOG2E 2.88539008177793f

__device__ __forceinline__ ushort_t f2h_bits(float f) {
    f16_t h = (f16_t)f;
    return __builtin_bit_cast(ushort_t, h);
}
__device__ __forceinline__ float h2f(ushort_t u) {
    return (float)__builtin_bit_cast(f16_t, u);
}
__device__ __forceinline__ float h2f_lo(uint_t u) { return h2f((ushort_t)(u & 0xFFFF)); }
__device__ __forceinline__ float h2f_hi(uint_t u) { return h2f((ushort_t)(u >> 16)); }

// Gate pre-activations PRE-SCALED by log2e (2*log2e for tanh g-gate) at pack
// time; v_rcp for the divide (no fast-math in harness). tanh=1-2/(1+e^{2g}).
__device__ __forceinline__ float sigm2(float x) {   // x prescaled by log2e
    return __builtin_amdgcn_rcpf(1.0f + __builtin_amdgcn_exp2f(-x));
}
__device__ __forceinline__ float tanh2(float y) {   // y prescaled by 2*log2e
    return __builtin_fmaf(-2.0f, __builtin_amdgcn_rcpf(1.0f + __builtin_amdgcn_exp2f(y)), 1.0f);
}
__device__ __forceinline__ float tanhc(float c) {   // c unscaled (cell state)
    return tanh2(c * TWO_LOG2E);
}

// B-fragment layout everywhere: frag(kt,q,n) at halves ((kt*4+q)*V + n)*8 + j,
// holding B[k][n] with k = kt*32 + q*8 + j. Consecutive n -> contiguous b128.
__device__ __forceinline__ half8_t ldfrag(const ushort_t* p, int V, int kt, int q, int n) {
    return *(const half8_t*)(p + ((size_t)((kt * 4 + q) * V + n)) * 8);
}

// R24: packAll vectorized 4 elements/thread. A 4-aligned k-group shares
// (kt,qq,v) -- j0 = k0&7 in {0,4} -- so the 4 output halves are contiguous:
// one ushort4 store (8B, aligned) replaces 4 scattered 2B stores. Groups
// never straddle the KA=128 source seam (128%4==0); per-element guards
// handle KA=257 / Ksrc=50 tails. 573K -> 143K stores.
__device__ __forceinline__ void pack4_one(
    const float* srcA, int KA, const float* srcB, int KB,
    ushort_t* dst, int V, int K, int g)
{
    int Kg = K >> 2;
    int v = g / Kg, k0 = (g - v * Kg) << 2;
    float sc = ((v >> 7) == 2) ? TWO_LOG2E : LOG2E;
    ushort_t h[4];
#pragma unroll
    for (int e = 0; e < 4; ++e) {
        int k = k0 + e;
        float val = 0.0f;
        if (k < KA) val = srcA[v * KA + k];
        else if (k < KA + KB) val = srcB[v * KB + (k - KA)];
        h[e] = f2h_bits(val * sc);
    }
    int kt = k0 >> 5, qq = (k0 >> 3) & 3, j0 = k0 & 7;
    *(ushort4*)(dst + ((size_t)((kt * 4 + qq) * V + v)) * 8 + j0) =
        make_ushort4(h[0], h[1], h[2], h[3]);
}

// t-LSTM variant: V=768, dead f-gate rows skipped (src row = v<256 ? v : v+256)
// -> packed gate order is i,g,o: v in [256,512) is the tanh g-gate.
__device__ __forceinline__ void pack4_tl(
    const float* src, int Ksrc, ushort_t* dst, int K, int g)
{
    int Kg = K >> 2;
    int v = g / Kg, k0 = (g - v * Kg) << 2;
    int r = (v < 256) ? v : v + 256;
    float sc = (v >= 256 && v < 512) ? TWO_LOG2E : LOG2E;
    ushort_t h[4];
#pragma unroll
    for (int e = 0; e < 4; ++e) {
        int k = k0 + e;
        float val = (k < Ksrc) ? src[r * Ksrc + k] : 0.0f;
        h[e] = f2h_bits(val * sc);
    }
    int kt = k0 >> 5, qq = (k0 >> 3) & 3, j0 = k0 & 7;
    *(ushort4*)(dst + ((size_t)((kt * 4 + qq) * 768 + v)) * 8 + j0) =
        make_ushort4(h[0], h[1], h[2], h[3]);
}

// All 5 weight packs fused into one launch; 143360 groups = 560 blocks x 256.
__global__ __launch_bounds__(256) void packAll(
    const float* __restrict__ tWih0, const float* __restrict__ tWih1,
    const float* __restrict__ nWih0, const float* __restrict__ nWhh0,
    const float* __restrict__ nWih1, const float* __restrict__ nWhh1,
    ushort_t* __restrict__ W0m, ushort_t* __restrict__ W1m,
    ushort_t* __restrict__ N0x, ushort_t* __restrict__ N0m,
    ushort_t* __restrict__ N1m)
{
    int g = blockIdx.x * 256 + threadIdx.x;
    if (g < 12288) { pack4_tl(tWih0, 50, W0m, 64, g); return; }
    g -= 12288;
    if (g < 49152) { pack4_tl(tWih1, 256, W1m, 256, g); return; }
    g -= 49152;
    if (g < 32768) { pack4_one(nWih0, 257, (const float*)0, 0, N0x, 512, 256, g); return; }
    g -= 32768;
    if (g < 16384) { pack4_one(nWhh0, 128, (const float*)0, 0, N0m, 512, 128, g); return; }
    g -= 16384;
    if (g < 32768) { pack4_one(nWih1, 128, nWhh1, 128, N1m, 512, 256, g); return; }
}

// fusedA R24 = R23 (64-row, waves_per_eu(4,4), proven no-spill ~76us) +
// explicit 1-kt-ahead B-frag prefetch in GEMM2 (the largest L2-load stream):
// the kt+1 frag loads issue above kt's 12 MFMAs, hiding ~200cy L2 latency.
// Transient regs: acc 48 + 2x12 frags + a 4 + misc ~= 110 <= 128 budget.
__global__ __launch_bounds__(512) __attribute__((amdgpu_waves_per_eu(4, 4)))
void fusedA(
    const float* __restrict__ note, const float* __restrict__ targets,
    const ushort_t* __restrict__ W0m, const float* __restrict__ b0,
    const ushort_t* __restrict__ W1m, const float* __restrict__ b1,
    const ushort_t* __restrict__ N0x, const float* __restrict__ nWih0raw,
    const float* __restrict__ nb0,
    uint_t* __restrict__ G1u)
{
    __shared__ __align__(16) ushort_t xAa[64 * 64];    //  8 KB
    __shared__ __align__(16) ushort_t xH1[64 * 256];   // 32 KB
    __shared__ __align__(16) ushort_t xH2[64 * 256];   // 32 KB
    const int tid = threadIdx.x;
    const int wv = tid >> 6, l = tid & 63, l16 = l & 15, q = l >> 4;
    const int r0A = blockIdx.x * 64;

    // staging: features (pitch_pos | pitch_class | vicinity | chord), K 56->64
    for (int idx = tid; idx < 64 * 64; idx += 512) {
        int r = idx >> 6, c = idx & 63;
        int row = r0A + r;
        int b = row / 48, n = row - b * 48;
        float val = 0.0f;
        if (c == 0) val = (float)n * (1.0f / 48.0f);
        else if (c < 13) val = ((n % 12) == (c - 1)) ? 1.0f : 0.0f;
        else if (c < 38) {
            int p = n + (c - 13) - 12;
            if (p >= 0 && p < 48) val = note[b * 48 + p];
        } else if (c < 50) {
            const float* nb = note + b * 48 + (c - 38) * 4;
            val = nb[0] + nb[1] + nb[2] + nb[3];
        }
        int kb = c >> 3, j = c & 7;
        xAa[r * 64 + (((kb ^ r) & 7) << 3) + j] = f2h_bits(val);
    }
    __syncthreads();

    // ---- GEMM1 (K=64) + gate -> xH1 ----
#pragma unroll
    for (int s = 0; s < 2; ++s) {
        const int u = (wv * 2 + s) * 16 + l16;
        floatx4 acc[4][3] = {};
#pragma unroll
        for (int kt = 0; kt < 2; ++kt) {
            half8_t bI = ldfrag(W0m, 768, kt, q, u);
            half8_t bG = ldfrag(W0m, 768, kt, q, 256 + u);
            half8_t bO = ldfrag(W0m, 768, kt, q, 512 + u);
            int kbp = ((kt * 4 + q) ^ l16) & 7;
#pragma unroll
            for (int mt = 0; mt < 4; ++mt) {
                half8_t a = *(const half8_t*)&xAa[(mt * 16 + l16) * 64 + kbp * 8];
                acc[mt][0] = __builtin_amdgcn_mfma_f32_16x16x32_f16(a, bI, acc[mt][0], 0, 0, 0);
                acc[mt][1] = __builtin_amdgcn_mfma_f32_16x16x32_f16(a, bG, acc[mt][1], 0, 0, 0);
                acc[mt][2] = __builtin_amdgcn_mfma_f32_16x16x32_f16(a, bO, acc[mt][2], 0, 0, 0);
            }
        }
        float bi = b0[u] * LOG2E, bg = b0[512 + u] * TWO_LOG2E, bo = b0[768 + u] * LOG2E;
        int kbW = u >> 3;
#pragma unroll
        for (int mt = 0; mt < 4; ++mt)
#pragma unroll
            for (int r = 0; r < 4; ++r) {
                float c = sigm2(acc[mt][0][r] + bi) * tanh2(acc[mt][1][r] + bg);
                float h = sigm2(acc[mt][2][r] + bo) * tanhc(c);
                int m = mt * 16 + q * 4 + r;
                int kbp = (kbW & 16) | ((kbW ^ (m & 15)) & 15);
                xH1[m * 256 + kbp * 8 + (u & 7)] = f2h_bits(h);
            }
    }
    __syncthreads();

    // ---- GEMM2 (K=256) + gate -> xH2 (B-frags prefetched 1 kt ahead) ----
#pragma unroll
    for (int s = 0; s < 2; ++s) {
        const int u = (wv * 2 + s) * 16 + l16;
        floatx4 acc[4][3] = {};
        half8_t bI = ldfrag(W1m, 768, 0, q, u);
        half8_t bG = ldfrag(W1m, 768, 0, q, 256 + u);
        half8_t bO = ldfrag(W1m, 768, 0, q, 512 + u);
#pragma unroll
        for (int kt = 0; kt < 8; ++kt) {
            half8_t nI, nG, nO;
            if (kt < 7) {
                nI = ldfrag(W1m, 768, kt + 1, q, u);
                nG = ldfrag(W1m, 768, kt + 1, q, 256 + u);
                nO = ldfrag(W1m, 768, kt + 1, q, 512 + u);
            }
            int kb = kt * 4 + q;
            int kbp = (kb & 16) | ((kb ^ l16) & 15);
#pragma unroll
            for (int mt = 0; mt < 4; ++mt) {
                half8_t a = *(const half8_t*)&xH1[(mt * 16 + l16) * 256 + kbp * 8];
                acc[mt][0] = __builtin_amdgcn_mfma_f32_16x16x32_f16(a, bI, acc[mt][0], 0, 0, 0);
                acc[mt][1] = __builtin_amdgcn_mfma_f32_16x16x32_f16(a, bG, acc[mt][1], 0, 0, 0);
                acc[mt][2] = __builtin_amdgcn_mfma_f32_16x16x32_f16(a, bO, acc[mt][2], 0, 0, 0);
            }
            if (kt < 7) { bI = nI; bG = nG; bO = nO; }
        }
        float bi = b1[u] * LOG2E, bg = b1[512 + u] * TWO_LOG2E, bo = b1[768 + u] * LOG2E;
        int kbW = u >> 3;
#pragma unroll
        for (int mt = 0; mt < 4; ++mt)
#pragma unroll
            for (int r = 0; r < 4; ++r) {
                float c = sigm2(acc[mt][0][r] + bi) * tanh2(acc[mt][1][r] + bg);
                float h = sigm2(acc[mt][2][r] + bo) * tanhc(c);
                int m = mt * 16 + q * 4 + r;
                int kbp = (kbW & 16) | ((kbW ^ (m & 15)) & 15);
                xH2[m * 256 + kbp * 8 + (u & 7)] = f2h_bits(h);
            }
    }
    __syncthreads();

    // ---- GEMM3 (K=256) + bias + cond rank-1 -> G1 (coalesced uint2 stores) ----
    {
        const int u2 = wv * 16 + l16;
        floatx4 acc[4][4] = {};
#pragma unroll
        for (int kt = 0; kt < 8; ++kt) {
            half8_t bf[4];
#pragma unroll
            for (int g = 0; g < 4; ++g) bf[g] = ldfrag(N0x, 512, kt, q, g * 128 + u2);
            int kb = kt * 4 + q;
            int kbp = (kb & 16) | ((kb ^ l16) & 15);
#pragma unroll
            for (int mt = 0; mt < 4; ++mt) {
                half8_t a = *(const half8_t*)&xH2[(mt * 16 + l16) * 256 + kbp * 8];
#pragma unroll
                for (int g = 0; g < 4; ++g)
                    acc[mt][g] = __builtin_amdgcn_mfma_f32_16x16x32_f16(a, bf[g], acc[mt][g], 0, 0, 0);
            }
        }
        float bias[4], wc[4];
#pragma unroll
        for (int g = 0; g < 4; ++g) {
            float sc = (g == 2) ? TWO_LOG2E : LOG2E;
            bias[g] = nb0[g * 128 + u2] * sc;
            wc[g] = nWih0raw[(size_t)(g * 128 + u2) * 257 + 256] * sc;
        }
#pragma unroll
        for (int mt = 0; mt < 4; ++mt) {
#pragma unroll
            for (int r = 0; r < 4; ++r) {
                int R = r0A + mt * 16 + q * 4 + r;
                int b = R / 48;
                int t = R - b * 48;
                float cond = (t > 0) ? targets[R - 1] : 0.0f;
                float vi = acc[mt][0][r] + bias[0] + cond * wc[0];
                float vf = acc[mt][1][r] + bias[1] + cond * wc[1];
                float vg = acc[mt][2][r] + bias[2] + cond * wc[2];
                float vo = acc[mt][3][r] + bias[3] + cond * wc[3];
                uint_t lo = (uint_t)f2h_bits(vi) | ((uint_t)f2h_bits(vf) << 16);
                uint_t hi = (uint_t)f2h_bits(vg) | ((uint_t)f2h_bits(vo) << 16);
                size_t a = ((size_t)(b >> 4) * 48 + t) * 4096 + (b & 15) * 256 + u2 * 2;
                *(uint2*)(G1u + a) = make_uint2(lo, hi);
            }
        }
    }
}

// phaseB: R17/R21 (measured 109.7us, VGPR 120, no spills) -- byte-identical.
// Near its trans-VALU issue floor: 64-block parallelism is algorithm-capped
// (B/16); per-SIMD gate-transcendental sum is occupancy-invariant.
#define MFMA_L1(ACC, A1) do { \
    _Pragma("unroll") for (int kt = 0; kt < 4; ++kt) { \
        int kb = kt * 4 + q; \
        _Pragma("unroll") for (int g = 0; g < 4; ++g) { \
            half8_t bfr = *(const half8_t*)&w1s[((size_t)(kb * 512 + g * 128 + u)) * 8]; \
            ACC[g] = __builtin_amdgcn_mfma_f32_16x16x32_f16(A1[kt], bfr, ACC[g], 0, 0, 0); \
        } } } while (0)

#define MFMA_L2(ACC, A1, A2) do { \
    _Pragma("unroll") for (int kt = 0; kt < 4; ++kt) \
        _Pragma("unroll") for (int g = 0; g < 4; ++g) \
            ACC[g] = __builtin_amdgcn_mfma_f32_16x16x32_f16( \
                A2[kt], __builtin_bit_cast(half8_t, B2[kt + 4][g]), ACC[g], 0, 0, 0); \
    _Pragma("unroll") for (int kt = 0; kt < 4; ++kt) \
        _Pragma("unroll") for (int g = 0; g < 4; ++g) \
            ACC[g] = __builtin_amdgcn_mfma_f32_16x16x32_f16( \
                A1[kt], __builtin_bit_cast(half8_t, B2[kt][g]), ACC[g], 0, 0, 0); \
    } while (0)

#define DO_E2(ACC) do { \
    _Pragma("unroll") for (int r = 0; r < 4; ++r) { \
        float gi = ACC[0][r] + bI; \
        float gf = ACC[1][r] + bF; \
        float gg = ACC[2][r] + bG; \
        float go = ACC[3][r] + bO; \
        c2[r] = sigm2(gf) * c2[r] + sigm2(gi) * tanh2(gg); \
        float h2v = sigm2(go) * tanhc(c2[r]); \
        int m = q * 4 + r; \
        xA[m * 512 + 256 + c + (((kbW ^ m) & 15) << 3) + jW] = f2h_bits(h2v); \
    } } while (0)

#define DO_E1(ACC, GS) do { \
    if (t < 47) { \
        _Pragma("unroll") for (int r = 0; r < 4; ++r) { \
            float gi = ACC[0][r] + h2f_lo(GS[r].x); \
            float gf = ACC[1][r] + h2f_hi(GS[r].x); \
            float gg = ACC[2][r] + h2f_lo(GS[r].y); \
            float go = ACC[3][r] + h2f_hi(GS[r].y); \
            c1[r] = sigm2(gf) * c1[r] + sigm2(gi) * tanh2(gg); \
            float h1v = sigm2(go) * tanhc(c1[r]); \
            int m = q * 4 + r; \
            xA[m * 512 + pv + (((kbW ^ m) & 15) << 3) + jW] = f2h_bits(h1v); \
        } } } while (0)

#define PREF_G1(DST) do { \
    int tn = (t < 46) ? t + 2 : 47; \
    const uint_t* gp = g1base + (size_t)tn * 4096; \
    _Pragma("unroll") for (int r = 0; r < 4; ++r) \
        DST[r] = *(const uint2*)(gp + (q * 4 + r) * 256 + u * 2); \
    } while (0)

__global__ __launch_bounds__(512) __attribute__((amdgpu_waves_per_eu(2, 2)))
void phaseB(
    const uint_t* __restrict__ G1u, const ushort_t* __restrict__ N0m,
    const ushort_t* __restrict__ N1m, const float* __restrict__ nb1,
    const float* __restrict__ outW, const float* __restrict__ outb,
    float* __restrict__ out)
{
    __shared__ __align__(16) ushort_t w1s[16 * 512 * 8];  // 131072 B (Whh0 frags)
    __shared__ __align__(16) ushort_t xA[16 * 512];       // [m][h1b0|h1b1|h2b0|h2b1]
    __shared__ __align__(16) ushort_t owfs[128];          // outW B-frag table, 256 B
    const int tid = threadIdx.x;
    const int wv = tid >> 6, l = tid & 63, l16 = l & 15, q = l >> 4;
    const int role = (wv ^ (wv >> 2)) & 1;
    const int r0 = blockIdx.x * 16;
    const int u = wv * 16 + l16;                 // unit 0..127

    for (int i = tid; i < 8192; i += 512) ((uint4*)w1s)[i] = ((const uint4*)N0m)[i];
    for (int i = tid; i < 1024; i += 512) ((uint4*)xA)[i] = make_uint4(0, 0, 0, 0);
    if (tid < 16) {
        int base = (tid >> 2) * 32 + (tid & 3) * 8;
#pragma unroll
        for (int j = 0; j < 8; ++j)
            owfs[tid * 8 + j] = f2h_bits(outW[base + j] * LOG2E);
    }

    // persistent L2-layer B-frags (128 regs)
    uintx4 B2[8][4];
#pragma unroll
    for (int kt = 0; kt < 8; ++kt)
#pragma unroll
        for (int g = 0; g < 4; ++g)
            B2[kt][g] = *(const uintx4*)(N1m + ((size_t)((kt * 4 + q) * 512 + g * 128 + u)) * 8);

    const float bI = nb1[u] * LOG2E, bF = nb1[128 + u] * LOG2E;
    const float bG = nb1[256 + u] * TWO_LOG2E, bO = nb1[384 + u] * LOG2E;
    const float obs = outb[0] * LOG2E;
    float c1[4], c2[4] = {0, 0, 0, 0};

    const uint_t* g1base = G1u + (size_t)blockIdx.x * 48 * 4096;
    uint2 g1c[4], g1x[4];
#pragma unroll
    for (int r = 0; r < 4; ++r)
        g1c[r] = *(const uint2*)(g1base + (q * 4 + r) * 256 + u * 2);

    const int kbW = u >> 3;   // 0..15
    const int jW = u & 7;

    __syncthreads();   // xA zero + w1s + owfs staged

    // Prologue E1(0): h1(0) from G1(0) only (h1(-1)=0 -> no Whh0 term; c1(-1)=0)
#pragma unroll
    for (int r = 0; r < 4; ++r) {
        float gi = h2f_lo(g1c[r].x);
        float gg = h2f_lo(g1c[r].y);
        float go = h2f_hi(g1c[r].y);
        c1[r] = sigm2(gi) * tanh2(gg);
        float h1v = sigm2(go) * tanhc(c1[r]);
        int m = q * 4 + r;
        xA[m * 512 + (((kbW ^ m) & 15) << 3) + jW] = f2h_bits(h1v);
    }
    // g1c <- G1(1) for region t=0's E1(1)
#pragma unroll
    for (int r = 0; r < 4; ++r)
        g1c[r] = *(const uint2*)(g1base + 4096 + (q * 4 + r) * 256 + u * 2);
    __syncthreads();   // h1(0) visible

    for (int t = 0; t < 48; ++t) {
        // Residency pin: asm "modifies" B2 each iteration -> reload illegal.
#pragma unroll
        for (int kt = 0; kt < 8; ++kt)
#pragma unroll
            for (int g = 0; g < 4; ++g)
                asm volatile("" : "+v"(B2[kt][g]));

        const int c = (t & 1) * 128;   // h1(t) base; h2(t) at 256+c
        const int pv = c ^ 128;        // h1(t+1) dest; h2(t-1) at 256+pv

        // A-fragments: h1(t) (shared by L2-partB and L1) and h2(t-1)
        half8_t a1[4], a2[4];
#pragma unroll
        for (int kt = 0; kt < 4; ++kt) {
            int kb = kt * 4 + q;
            int kbp = (kb ^ l16) & 15;
            a1[kt] = *(const half8_t*)&xA[l16 * 512 + c + kbp * 8];
            a2[kt] = *(const half8_t*)&xA[l16 * 512 + 256 + pv + kbp * 8];
        }

        if (role == 0) {
            // ===== role E: L2 -> E2 -> L1 -> E1 =====
            floatx4 acc2[4] = {};
            MFMA_L2(acc2, a1, a2);
            if (wv == 0) {   // head(t-1) = outW . h2(t-1), wave 0 only
                floatx4 accH = {0.0f, 0.0f, 0.0f, 0.0f};
#pragma unroll
                for (int kt = 0; kt < 4; ++kt) {
                    half8_t of = *(const half8_t*)&owfs[(kt * 4 + q) * 8];
                    accH = __builtin_amdgcn_mfma_f32_16x16x32_f16(a2[kt], of, accH, 0, 0, 0);
                }
                if (t > 0 && l16 == 0) {
#pragma unroll
                    for (int r = 0; r < 4; ++r)
                        out[(r0 + q * 4 + r) * 48 + (t - 1)] = sigm2(accH[r] + obs);
                }
            }
            DO_E2(acc2);
            PREF_G1(g1x);             // early: covered before barrier drain
            floatx4 acc1[4] = {};
            MFMA_L1(acc1, a1);
            DO_E1(acc1, g1c);
#pragma unroll
            for (int r = 0; r < 4; ++r) g1c[r] = g1x[r];
        } else {
            // ===== role O: L1 -> E1 -> L2 -> E2 =====
            floatx4 acc1[4] = {};
            MFMA_L1(acc1, a1);
            DO_E1(acc1, g1c);
            PREF_G1(g1c);             // g1c consumed above; refill directly
            floatx4 acc2[4] = {};
            MFMA_L2(acc2, a1, a2);
            DO_E2(acc2);
        }
        __syncthreads();   // h1(t+1), h2(t) sealed
    }

    // Epilogue: head(47) from h2(47) (at 256+128 after the t=47 region)
    if (wv == 0) {
        floatx4 accH = {0.0f, 0.0f, 0.0f, 0.0f};
#pragma unroll
        for (int kt = 0; kt < 4; ++kt) {
            int kb = kt * 4 + q;
            int kbp = (kb ^ l16) & 15;
            half8_t a2e = *(const half8_t*)&xA[l16 * 512 + 256 + 128 + kbp * 8];
            half8_t of = *(const half8_t*)&owfs[(kt * 4 + q) * 8];
            accH = __builtin_amdgcn_mfma_f32_16x16x32_f16(a2e, of, accH, 0, 0, 0);
        }
        if (l16 == 0) {
#pragma unroll
            for (int r = 0; r < 4; ++r)
                out[(r0 + q * 4 + r) * 48 + 47] = sigm2(accH[r] + obs);
        }
    }
}

extern "C" void kernel_launch(void* const* d_in, const int* in_sizes, int n_in,
                              void* d_out, int out_size, void* d_ws, size_t ws_size,
                              hipStream_t stream)
{
    const float* note  = (const float*)d_in[0];
    const float* targ  = (const float*)d_in[1];
    const float* tWih0 = (const float*)d_in[2];
    const float* tb0   = (const float*)d_in[4];
    const float* tWih1 = (const float*)d_in[5];
    const float* tb1   = (const float*)d_in[7];
    const float* nWih0 = (const float*)d_in[8];
    const float* nWhh0 = (const float*)d_in[9];
    const float* nb0   = (const float*)d_in[10];
    const float* nWih1 = (const float*)d_in[11];
    const float* nWhh1 = (const float*)d_in[12];
    const float* nb1   = (const float*)d_in[13];
    const float* outW  = (const float*)d_in[14];
    const float* outb  = (const float*)d_in[15];

    char* ws = (char*)d_ws;
    uint_t*   G1u = (uint_t*)(ws);                // 64*48*4096 uints = 50331648 B
    ushort_t* W0m = (ushort_t*)(ws + 50331648);   //  98304 B
    ushort_t* W1m = (ushort_t*)(ws + 50429952);   // 393216 B
    ushort_t* N0x = (ushort_t*)(ws + 50823168);   // 262144 B
    ushort_t* N0m = (ushort_t*)(ws + 51085312);   // 131072 B
    ushort_t* N1m = (ushort_t*)(ws + 51216384);   // 262144 B

    packAll<<<560, 256, 0, stream>>>(tWih0, tWih1, nWih0, nWhh0, nWih1, nWhh1,
                                     W0m, W1m, N0x, N0m, N1m);
    fusedA<<<768, 512, 0, stream>>>(note, targ, W0m, tb0, W1m, tb1, N0x, nWih0, nb0, G1u);
    phaseB<<<64, 512, 0, stream>>>(G1u, N0m, N1m, nb1, outW, outb, (float*)d_out);
}